// Round 1
// baseline (100.429 us; speedup 1.0000x reference)
//
#include <hip/hip_runtime.h>

typedef float  f32x4  __attribute__((ext_vector_type(4)));
typedef short  s16x8  __attribute__((ext_vector_type(8)));
typedef short  s16x4  __attribute__((ext_vector_type(4)));

__device__ __forceinline__ unsigned short f2bf(float f) {
    unsigned int u = __float_as_uint(f);
    return (unsigned short)((u + 0x7FFFu + ((u >> 16) & 1u)) >> 16);
}

// ---------------------------------------------------------------------------
// Kernel 0: build Wt bf16 [384][1024]: Wt[n][k] = W_sel[k][n&127]
// n in [0,128) -> Wq, [128,256) -> Wk, [256,384) -> Wv
// ---------------------------------------------------------------------------
__global__ void prep_wt(const float* __restrict__ Wq,
                        const float* __restrict__ Wk,
                        const float* __restrict__ Wv,
                        unsigned short* __restrict__ wt) {
    int n = blockIdx.x;                       // 0..383
    const float* W = (n < 128) ? Wq : ((n < 256) ? Wk : Wv);
    int h = n & 127;
    for (int k = threadIdx.x; k < 1024; k += blockDim.x) {
        wt[(size_t)n * 1024 + k] = f2bf(W[(size_t)k * 128 + h]);
    }
}

// ---------------------------------------------------------------------------
// Kernel 1: QKV GEMM.  A = x f32 [32768][1024] (converted to bf16 on the fly),
// B = Wt bf16 [384][1024] (k-contiguous).  BM=128, BN=384, BK=64, 8 waves.
// Outputs: Q,K bf16 [B*T][128]; V transposed bf16 [B][128][256].
// ---------------------------------------------------------------------------
__global__ __launch_bounds__(512) void qkv_gemm(
    const float* __restrict__ x,
    const unsigned short* __restrict__ wt,
    unsigned short* __restrict__ qo,
    unsigned short* __restrict__ ko,
    unsigned short* __restrict__ vto) {

    __shared__ char smem[65536];              // A: [0,16K) , B: [16K,64K)

    const int tid = threadIdx.x;
    const int bm  = blockIdx.x;               // 0..255 (M tiles of 128)
    const int lane = tid & 63, wid = tid >> 6;
    const int lm = lane & 15, l4 = lane >> 4;
    const int wm = wid >> 2, wn = wid & 3;    // wave grid 2 (M) x 4 (N)

    f32x4 acc[4][6];
#pragma unroll
    for (int i = 0; i < 4; ++i)
#pragma unroll
        for (int j = 0; j < 6; ++j) acc[i][j] = (f32x4)0.f;

    // A staging geometry: thread -> row tid>>2, 16 consecutive f32
    const int ar  = tid >> 2;                 // 0..127
    const int ac0 = (tid & 3) << 4;           // 0,16,32,48
    const float* xbase = x + (size_t)(bm * 128 + ar) * 1024 + ac0;
    const int aw0 = ar * 128 + (((ac0 * 2)      ) ^ ((ar & 7) << 4));
    const int aw1 = ar * 128 + (((ac0 * 2) + 16 ) ^ ((ar & 7) << 4));

    for (int ks = 0; ks < 16; ++ks) {
        __syncthreads();
        // ---- stage A (f32 -> bf16, swizzled) ----
        const float* xp = xbase + ks * 64;
        f32x4 v0 = *(const f32x4*)(xp + 0);
        f32x4 v1 = *(const f32x4*)(xp + 4);
        f32x4 v2 = *(const f32x4*)(xp + 8);
        f32x4 v3 = *(const f32x4*)(xp + 12);
        s16x8 h0, h1;
#pragma unroll
        for (int j = 0; j < 4; ++j) {
            h0[j]     = (short)f2bf(v0[j]);
            h0[j + 4] = (short)f2bf(v1[j]);
            h1[j]     = (short)f2bf(v2[j]);
            h1[j + 4] = (short)f2bf(v3[j]);
        }
        *(s16x8*)(smem + aw0) = h0;
        *(s16x8*)(smem + aw1) = h1;
        // ---- stage B (bf16 copy, swizzled) ----
#pragma unroll
        for (int i = 0; i < 6; ++i) {
            int chunk = i * 512 + tid;        // 0..3071
            int n  = chunk >> 3;              // 0..383
            int c8 = chunk & 7;               // 16B chunk within row
            s16x8 w = *(const s16x8*)(wt + (size_t)n * 1024 + ks * 64 + c8 * 8);
            *(s16x8*)(smem + 16384 + n * 128 + ((c8 * 16) ^ ((n & 7) << 4))) = w;
        }
        __syncthreads();
        // ---- MFMA ----
#pragma unroll
        for (int kkk = 0; kkk < 2; ++kkk) {
            s16x8 a[4], bfr[6];
#pragma unroll
            for (int mi = 0; mi < 4; ++mi) {
                int row = wm * 64 + mi * 16 + lm;
                a[mi] = *(const s16x8*)(smem + row * 128 +
                          ((kkk * 64 + l4 * 16) ^ ((row & 7) << 4)));
            }
#pragma unroll
            for (int ni = 0; ni < 6; ++ni) {
                int n = wn * 96 + ni * 16 + lm;
                bfr[ni] = *(const s16x8*)(smem + 16384 + n * 128 +
                          ((kkk * 64 + l4 * 16) ^ ((n & 7) << 4)));
            }
#pragma unroll
            for (int mi = 0; mi < 4; ++mi)
#pragma unroll
                for (int ni = 0; ni < 6; ++ni)
                    acc[mi][ni] = __builtin_amdgcn_mfma_f32_16x16x32_bf16(
                        a[mi], bfr[ni], acc[mi][ni], 0, 0, 0);
        }
    }

    // ---- epilogue ----
#pragma unroll
    for (int mi = 0; mi < 4; ++mi) {
        int m0 = bm * 128 + wm * 64 + mi * 16 + l4 * 4;  // global row (j adds 0..3)
#pragma unroll
        for (int ni = 0; ni < 6; ++ni) {
            int nb  = wn * 96 + ni * 16;
            int mat = nb >> 7;                 // 0=Q 1=K 2=V
            int col = (nb & 127) + lm;
            if (mat == 2) {
                int bb = m0 >> 8, t = m0 & 255;
                s16x4 w4;
#pragma unroll
                for (int j = 0; j < 4; ++j) w4[j] = (short)f2bf(acc[mi][ni][j]);
                *(s16x4*)(vto + ((size_t)bb * 128 + col) * 256 + t) = w4;
            } else {
                unsigned short* dst = (mat == 0) ? qo : ko;
#pragma unroll
                for (int j = 0; j < 4; ++j)
                    dst[(size_t)(m0 + j) * 128 + col] = f2bf(acc[mi][ni][j]);
            }
        }
    }
}

// ---------------------------------------------------------------------------
// Kernel 2: causal attention.  2 blocks per batch (q-tiles of 128 rows),
// 8 waves x 16 q-rows.  Swapped QK^T (S^T = mfma(K,Q)) so softmax reduction
// is 2 shfl_xor; P packed to swizzled LDS; PV swapped (out^T = mfma(V^T,P^T))
// giving contiguous float4 output stores.
// ---------------------------------------------------------------------------
__global__ __launch_bounds__(512) void attn(
    const unsigned short* __restrict__ q,
    const unsigned short* __restrict__ k,
    const unsigned short* __restrict__ vt,
    float* __restrict__ out) {

    __shared__ char pbuf[65536];               // 8 waves x [16][256] bf16

    const int tid = threadIdx.x, wid = tid >> 6, lane = tid & 63;
    const int lm = lane & 15, l4 = lane >> 4;
    const int b = blockIdx.x >> 1, qt = blockIdx.x & 1;
    const int qbase = qt << 7;
    const int t0 = qbase + wid * 16;
    const int nfrags = (qbase + 128) >> 4;     // 8 or 16 (kv 16-frags)
    const int nkf    = (qbase + 128) >> 5;     // 4 or 8  (kv 32-frags)

    // Q fragments (B-operand: col = t = lm, 8 contiguous h per lane)
    const unsigned short* qrow = q + (size_t)(b * 256 + t0 + lm) * 128 + l4 * 8;
    s16x8 qf[4];
#pragma unroll
    for (int kf = 0; kf < 4; ++kf) qf[kf] = *(const s16x8*)(qrow + kf * 32);

    // S^T accumulators: col = t (lm), row = kv = nf*16 + l4*4 + j
    f32x4 sacc[16];
#pragma unroll
    for (int i = 0; i < 16; ++i) sacc[i] = (f32x4)0.f;

    const unsigned short* kbase = k + (size_t)(b * 256) * 128 + l4 * 8;
#pragma unroll
    for (int nf = 0; nf < 16; ++nf) {
        if (nf < nfrags) {
#pragma unroll
            for (int kf = 0; kf < 4; ++kf) {
                s16x8 a = *(const s16x8*)(kbase + (size_t)(nf * 16 + lm) * 128 + kf * 32);
                sacc[nf] = __builtin_amdgcn_mfma_f32_16x16x32_bf16(a, qf[kf], sacc[nf], 0, 0, 0);
            }
        }
    }

    // ---- mask + scale + softmax (per column t = t0+lm) ----
    const float scale = 0.08838834764831845f;  // 1/sqrt(128)
    const int tg = t0 + lm;
    float mx = -1e30f;
#pragma unroll
    for (int nf = 0; nf < 16; ++nf) {
        if (nf < nfrags) {
#pragma unroll
            for (int j = 0; j < 4; ++j) {
                int kv = nf * 16 + l4 * 4 + j;
                float s = sacc[nf][j] * scale;
                s = (kv > tg) ? -1e30f : s;
                sacc[nf][j] = s;
                mx = fmaxf(mx, s);
            }
        }
    }
    mx = fmaxf(mx, __shfl_xor(mx, 16));
    mx = fmaxf(mx, __shfl_xor(mx, 32));
    float sum = 0.f;
#pragma unroll
    for (int nf = 0; nf < 16; ++nf) {
        if (nf < nfrags) {
#pragma unroll
            for (int j = 0; j < 4; ++j) {
                float p = __expf(sacc[nf][j] - mx);
                sacc[nf][j] = p;
                sum += p;
            }
        }
    }
    sum += __shfl_xor(sum, 16);
    sum += __shfl_xor(sum, 32);
    float rinv = 1.0f / sum;

    // ---- pack P to LDS: layout [t=16][kv=256] bf16, XOR-swizzled ----
    char* pw = pbuf + wid * 8192 + lm * 512;
#pragma unroll
    for (int nf = 0; nf < 16; ++nf) {
        if (nf < nfrags) {
            s16x4 w;
#pragma unroll
            for (int j = 0; j < 4; ++j) w[j] = (short)f2bf(sacc[nf][j] * rinv);
            *(s16x4*)(pw + ((nf * 32 + l4 * 8) ^ ((lm & 7) << 4))) = w;
        }
    }
    asm volatile("s_waitcnt lgkmcnt(0)" ::: "memory");

    // ---- PV: out^T = V^T (A) x P^T (B) ----
    f32x4 oacc[8];
#pragma unroll
    for (int i = 0; i < 8; ++i) oacc[i] = (f32x4)0.f;

    const unsigned short* vbase = vt + (size_t)b * 32768 + l4 * 8;
#pragma unroll
    for (int kvf = 0; kvf < 8; ++kvf) {
        if (kvf < nkf) {
            s16x8 pf = *(const s16x8*)(pbuf + wid * 8192 + lm * 512 +
                        ((kvf * 64 + l4 * 16) ^ ((lm & 7) << 4)));
#pragma unroll
            for (int hf = 0; hf < 8; ++hf) {
                s16x8 a = *(const s16x8*)(vbase + (size_t)(hf * 16 + lm) * 256 + kvf * 32);
                oacc[hf] = __builtin_amdgcn_mfma_f32_16x16x32_bf16(a, pf, oacc[hf], 0, 0, 0);
            }
        }
    }

    // ---- store out[b][t][h] f32, contiguous float4 per lane ----
    float* ob = out + (size_t)(b * 256 + t0 + lm) * 128 + l4 * 4;
#pragma unroll
    for (int hf = 0; hf < 8; ++hf)
        *(f32x4*)(ob + hf * 16) = oacc[hf];
}

// ---------------------------------------------------------------------------
extern "C" void kernel_launch(void* const* d_in, const int* in_sizes, int n_in,
                              void* d_out, int out_size, void* d_ws, size_t ws_size,
                              hipStream_t stream) {
    const float* x  = (const float*)d_in[0];
    const float* Wq = (const float*)d_in[1];
    const float* Wk = (const float*)d_in[2];
    const float* Wv = (const float*)d_in[3];
    float* out = (float*)d_out;

    char* ws = (char*)d_ws;
    unsigned short* wt = (unsigned short*)(ws);                    // 384*1024*2   = 786432
    unsigned short* qb = (unsigned short*)(ws + 786432);           // 32768*128*2  = 8388608
    unsigned short* kb = (unsigned short*)(ws + 786432 + 8388608);
    unsigned short* vb = (unsigned short*)(ws + 786432 + 2 * 8388608);

    prep_wt<<<384, 256, 0, stream>>>(Wq, Wk, Wv, wt);
    qkv_gemm<<<256, 512, 0, stream>>>(x, wt, qb, kb, vb);
    attn<<<256, 512, 0, stream>>>(qb, kb, vb, out);
}

// Round 2
// 83.051 us; speedup vs baseline: 1.2092x; 1.2092x over previous
//
#include <hip/hip_runtime.h>

typedef float  f32x4  __attribute__((ext_vector_type(4)));
typedef short  s16x8  __attribute__((ext_vector_type(8)));
typedef short  s16x4  __attribute__((ext_vector_type(4)));

__device__ __forceinline__ unsigned short f2bf(float f) {
    unsigned int u = __float_as_uint(f);
    return (unsigned short)((u + 0x7FFFu + ((u >> 16) & 1u)) >> 16);
}

// ---------------------------------------------------------------------------
// Kernel 0: build Wt bf16 [384][1024]: Wt[n][k] = W_sel[k][n&127]
// ---------------------------------------------------------------------------
__global__ void prep_wt(const float* __restrict__ Wq,
                        const float* __restrict__ Wk,
                        const float* __restrict__ Wv,
                        unsigned short* __restrict__ wt) {
    int n = blockIdx.x;                       // 0..383
    const float* W = (n < 128) ? Wq : ((n < 256) ? Wk : Wv);
    int h = n & 127;
    for (int k = threadIdx.x; k < 1024; k += blockDim.x) {
        wt[(size_t)n * 1024 + k] = f2bf(W[(size_t)k * 128 + h]);
    }
}

// ---------------------------------------------------------------------------
// Kernel 1: QKV GEMM.  BM=64, BN=384, BK=64, 8 waves (2M x 4N), grid 512
// -> 2 blocks/CU (LDS 56KB).  Register prefetch of next K-slab (A f32->bf16,
// B bf16) issued before the MFMA phase so HBM/L2 latency hides under MFMA
// and under the co-resident block (m114 overlap).
// Outputs: Q,K bf16 [B*T][128]; V transposed bf16 [B][128][256].
// ---------------------------------------------------------------------------
__global__ __launch_bounds__(512, 4) void qkv_gemm(
    const float* __restrict__ x,
    const unsigned short* __restrict__ wt,
    unsigned short* __restrict__ qo,
    unsigned short* __restrict__ ko,
    unsigned short* __restrict__ vto) {

    __shared__ char smem[57344];              // A: [0,8K) , B: [8K,56K)

    const int tid = threadIdx.x;
    const int bm  = blockIdx.x;               // 0..511 (M tiles of 64)
    const int lane = tid & 63, wid = tid >> 6;
    const int lm = lane & 15, l4 = lane >> 4;
    const int wm = wid >> 2, wn = wid & 3;    // wave grid 2 (M) x 4 (N)

    f32x4 acc[2][6];
#pragma unroll
    for (int i = 0; i < 2; ++i)
#pragma unroll
        for (int j = 0; j < 6; ++j) acc[i][j] = (f32x4)0.f;

    // ---- A staging geometry: thread -> row tid>>3, 8 consecutive f32 ----
    const int ar = tid >> 3;                  // 0..63
    const int ac = (tid & 7) << 3;            // f32 col 0..56
    const float* xbase = x + (size_t)(bm * 64 + ar) * 1024 + ac;
    const int awr = ar * 128 + (((tid & 7) << 4) ^ ((ar & 7) << 4));

    // ---- B staging geometry: 6 chunks of 16B per thread ----
    int boff[6], blds[6];
#pragma unroll
    for (int i = 0; i < 6; ++i) {
        int chunk = i * 512 + tid;            // 0..3071
        int n  = chunk >> 3;                  // 0..383
        int c8 = chunk & 7;
        boff[i] = n * 1024 + c8 * 8;          // element offset (add ks*64)
        blds[i] = 8192 + n * 128 + ((c8 * 16) ^ ((n & 7) << 4));
    }

    // ---- prologue: load slab 0 into regs ----
    f32x4 a0 = *(const f32x4*)(xbase);
    f32x4 a1 = *(const f32x4*)(xbase + 4);
    s16x8 bpre[6];
#pragma unroll
    for (int i = 0; i < 6; ++i) bpre[i] = *(const s16x8*)(wt + boff[i]);

    for (int ks = 0; ks < 16; ++ks) {
        __syncthreads();                      // prev MFMA phase done reading
        // ---- write staged regs -> LDS (swizzled) ----
        s16x8 h;
#pragma unroll
        for (int j = 0; j < 4; ++j) {
            h[j]     = (short)f2bf(a0[j]);
            h[j + 4] = (short)f2bf(a1[j]);
        }
        *(s16x8*)(smem + awr) = h;
#pragma unroll
        for (int i = 0; i < 6; ++i) *(s16x8*)(smem + blds[i]) = bpre[i];
        // ---- issue next slab's global loads (in flight during MFMA) ----
        if (ks < 15) {
            const float* xp = xbase + (ks + 1) * 64;
            a0 = *(const f32x4*)(xp);
            a1 = *(const f32x4*)(xp + 4);
#pragma unroll
            for (int i = 0; i < 6; ++i)
                bpre[i] = *(const s16x8*)(wt + boff[i] + (ks + 1) * 64);
        }
        __syncthreads();
        // ---- MFMA ----
#pragma unroll
        for (int kkk = 0; kkk < 2; ++kkk) {
            s16x8 a[2];
#pragma unroll
            for (int mi = 0; mi < 2; ++mi) {
                int row = wm * 32 + mi * 16 + lm;
                a[mi] = *(const s16x8*)(smem + row * 128 +
                          ((kkk * 64 + l4 * 16) ^ ((row & 7) << 4)));
            }
#pragma unroll
            for (int ni = 0; ni < 6; ++ni) {
                int n = wn * 96 + ni * 16 + lm;
                s16x8 bfr = *(const s16x8*)(smem + 8192 + n * 128 +
                          ((kkk * 64 + l4 * 16) ^ ((n & 7) << 4)));
#pragma unroll
                for (int mi = 0; mi < 2; ++mi)
                    acc[mi][ni] = __builtin_amdgcn_mfma_f32_16x16x32_bf16(
                        a[mi], bfr, acc[mi][ni], 0, 0, 0);
            }
        }
    }

    // ---- epilogue ----
#pragma unroll
    for (int mi = 0; mi < 2; ++mi) {
        int m0 = bm * 64 + wm * 32 + mi * 16 + l4 * 4;   // global row (j adds 0..3)
#pragma unroll
        for (int ni = 0; ni < 6; ++ni) {
            int nb  = wn * 96 + ni * 16;
            int mat = nb >> 7;                 // 0=Q 1=K 2=V
            int col = (nb & 127) + lm;
            if (mat == 2) {
                int bb = m0 >> 8, t = m0 & 255;
                s16x4 w4;
#pragma unroll
                for (int j = 0; j < 4; ++j) w4[j] = (short)f2bf(acc[mi][ni][j]);
                *(s16x4*)(vto + ((size_t)bb * 128 + col) * 256 + t) = w4;
            } else {
                unsigned short* dst = (mat == 0) ? qo : ko;
#pragma unroll
                for (int j = 0; j < 4; ++j)
                    dst[(size_t)(m0 + j) * 128 + col] = f2bf(acc[mi][ni][j]);
            }
        }
    }
}

// ---------------------------------------------------------------------------
// Kernel 2: causal attention.  2 blocks per batch (q-tiles of 128 rows),
// 8 waves x 16 q-rows.  Swapped QK^T (S^T = mfma(K,Q)) so softmax reduction
// is 2 shfl_xor; P packed to swizzled LDS; PV swapped (out^T = mfma(V^T,P^T))
// giving contiguous float4 output stores.
// ---------------------------------------------------------------------------
__global__ __launch_bounds__(512) void attn(
    const unsigned short* __restrict__ q,
    const unsigned short* __restrict__ k,
    const unsigned short* __restrict__ vt,
    float* __restrict__ out) {

    __shared__ char pbuf[65536];               // 8 waves x [16][256] bf16

    const int tid = threadIdx.x, wid = tid >> 6, lane = tid & 63;
    const int lm = lane & 15, l4 = lane >> 4;
    const int b = blockIdx.x >> 1, qt = blockIdx.x & 1;
    const int qbase = qt << 7;
    const int t0 = qbase + wid * 16;
    const int nfrags = (qbase + 128) >> 4;     // 8 or 16 (kv 16-frags)
    const int nkf    = (qbase + 128) >> 5;     // 4 or 8  (kv 32-frags)

    // Q fragments (B-operand: col = t = lm, 8 contiguous h per lane)
    const unsigned short* qrow = q + (size_t)(b * 256 + t0 + lm) * 128 + l4 * 8;
    s16x8 qf[4];
#pragma unroll
    for (int kf = 0; kf < 4; ++kf) qf[kf] = *(const s16x8*)(qrow + kf * 32);

    // S^T accumulators: col = t (lm), row = kv = nf*16 + l4*4 + j
    f32x4 sacc[16];
#pragma unroll
    for (int i = 0; i < 16; ++i) sacc[i] = (f32x4)0.f;

    const unsigned short* kbase = k + (size_t)(b * 256) * 128 + l4 * 8;
#pragma unroll
    for (int nf = 0; nf < 16; ++nf) {
        if (nf < nfrags) {
#pragma unroll
            for (int kf = 0; kf < 4; ++kf) {
                s16x8 a = *(const s16x8*)(kbase + (size_t)(nf * 16 + lm) * 128 + kf * 32);
                sacc[nf] = __builtin_amdgcn_mfma_f32_16x16x32_bf16(a, qf[kf], sacc[nf], 0, 0, 0);
            }
        }
    }

    // ---- mask + scale + softmax (per column t = t0+lm) ----
    const float scale = 0.08838834764831845f;  // 1/sqrt(128)
    const int tg = t0 + lm;
    float mx = -1e30f;
#pragma unroll
    for (int nf = 0; nf < 16; ++nf) {
        if (nf < nfrags) {
#pragma unroll
            for (int j = 0; j < 4; ++j) {
                int kv = nf * 16 + l4 * 4 + j;
                float s = sacc[nf][j] * scale;
                s = (kv > tg) ? -1e30f : s;
                sacc[nf][j] = s;
                mx = fmaxf(mx, s);
            }
        }
    }
    mx = fmaxf(mx, __shfl_xor(mx, 16));
    mx = fmaxf(mx, __shfl_xor(mx, 32));
    float sum = 0.f;
#pragma unroll
    for (int nf = 0; nf < 16; ++nf) {
        if (nf < nfrags) {
#pragma unroll
            for (int j = 0; j < 4; ++j) {
                float p = __expf(sacc[nf][j] - mx);
                sacc[nf][j] = p;
                sum += p;
            }
        }
    }
    sum += __shfl_xor(sum, 16);
    sum += __shfl_xor(sum, 32);
    float rinv = 1.0f / sum;

    // ---- pack P to LDS: layout [t=16][kv=256] bf16, XOR-swizzled ----
    char* pw = pbuf + wid * 8192 + lm * 512;
#pragma unroll
    for (int nf = 0; nf < 16; ++nf) {
        if (nf < nfrags) {
            s16x4 w;
#pragma unroll
            for (int j = 0; j < 4; ++j) w[j] = (short)f2bf(sacc[nf][j] * rinv);
            *(s16x4*)(pw + ((nf * 32 + l4 * 8) ^ ((lm & 7) << 4))) = w;
        }
    }
    asm volatile("s_waitcnt lgkmcnt(0)" ::: "memory");

    // ---- PV: out^T = V^T (A) x P^T (B) ----
    f32x4 oacc[8];
#pragma unroll
    for (int i = 0; i < 8; ++i) oacc[i] = (f32x4)0.f;

    const unsigned short* vbase = vt + (size_t)b * 32768 + l4 * 8;
#pragma unroll
    for (int kvf = 0; kvf < 8; ++kvf) {
        if (kvf < nkf) {
            s16x8 pf = *(const s16x8*)(pbuf + wid * 8192 + lm * 512 +
                        ((kvf * 64 + l4 * 16) ^ ((lm & 7) << 4)));
#pragma unroll
            for (int hf = 0; hf < 8; ++hf) {
                s16x8 a = *(const s16x8*)(vbase + (size_t)(hf * 16 + lm) * 256 + kvf * 32);
                oacc[hf] = __builtin_amdgcn_mfma_f32_16x16x32_bf16(a, pf, oacc[hf], 0, 0, 0);
            }
        }
    }

    // ---- store out[b][t][h] f32, contiguous float4 per lane ----
    float* ob = out + (size_t)(b * 256 + t0 + lm) * 128 + l4 * 4;
#pragma unroll
    for (int hf = 0; hf < 8; ++hf)
        *(f32x4*)(ob + hf * 16) = oacc[hf];
}

// ---------------------------------------------------------------------------
extern "C" void kernel_launch(void* const* d_in, const int* in_sizes, int n_in,
                              void* d_out, int out_size, void* d_ws, size_t ws_size,
                              hipStream_t stream) {
    const float* x  = (const float*)d_in[0];
    const float* Wq = (const float*)d_in[1];
    const float* Wk = (const float*)d_in[2];
    const float* Wv = (const float*)d_in[3];
    float* out = (float*)d_out;

    char* ws = (char*)d_ws;
    unsigned short* wt = (unsigned short*)(ws);                    // 384*1024*2   = 786432
    unsigned short* qb = (unsigned short*)(ws + 786432);           // 32768*128*2  = 8388608
    unsigned short* kb = (unsigned short*)(ws + 786432 + 8388608);
    unsigned short* vb = (unsigned short*)(ws + 786432 + 2 * 8388608);

    prep_wt<<<384, 256, 0, stream>>>(Wq, Wk, Wv, wt);
    qkv_gemm<<<512, 512, 0, stream>>>(x, wt, qb, kb, vb);
    attn<<<256, 512, 0, stream>>>(qb, kb, vb, out);
}